// Round 6
// baseline (170.842 us; speedup 1.0000x reference)
//
#include <hip/hip_runtime.h>

// Shape fixed by reference: (2,1,160,160,160) fp32, window 11, zero-pad box filter.
// Fields reduced via u=x+y, v=x-y: box{u, v, u^2, v^2} packed in one float4.
// v5 = v3 dataflow + :
//   - H-pass widened to 256 threads x 1 output, summing 11 wpf rows directly into
//     the Sv register -> Sb buffer, its round-trip, and barrier B2 eliminated
//     (1 barrier/iter). wpf double-buffered for single-barrier safety.
//   - final reduction fused into the last block (atomic counter + fences, same
//     double-precision order as the old final_reduce -> bit-identical output).
// (Resubmission: round-5 bench failed on GPU acquisition, no data.)
#define DIMX 160
#define DIMY 160
#define DIMZ 160
#define BC   2
#define NTOT (BC * DIMZ * DIMY * DIMX)   // 8,192,000
#define PLANE (DIMY * DIMX)
#define PAD  5
#define TS   16                  // tile size in H and W
#define HS   26                  // TS + 2*PAD rows
#define XS4  10                  // stage row stride in float4 (8 used + 2 pad)
#define BUF  (HS * XS4)          // one u/v slab buffer in float4 (260)
#define WPS  17                  // wpf row stride in float4
#define WPB  (HS * WPS)          // one wpf buffer in float4 (442)
#define CD   32                  // D-chunk per block
#define NCH  (DIMZ / CD)         // 5
#define NTH  (DIMY / TS)         // 10
#define NTW  (DIMX / TS)         // 10
#define NBLK (NCH * BC * NTH * NTW)  // 1000 blocks

static_assert(NTOT == 8192000, "size mismatch");
static_assert(NCH * CD == DIMZ, "CD must divide DIMZ");

__device__ __forceinline__ float4 f4add(float4 a, float4 b) {
  return make_float4(a.x + b.x, a.y + b.y, a.z + b.z, a.w + b.w);
}
__device__ __forceinline__ float4 f4sub(float4 a, float4 b) {
  return make_float4(a.x - b.x, a.y - b.y, a.z - b.z, a.w - b.w);
}

// Ring slot update with compile-time index K (keeps ring[] in VGPRs).
#define RING_CASE(K) case K: {                 \
    sums = f4add(sums, f4sub(Sv, ring[K]));    \
    ring[K] = Sv;                              \
  } break;

__global__ __launch_bounds__(256) void fused_ssim(const float* __restrict__ X,
                                                  const float* __restrict__ Y,
                                                  float* __restrict__ pssim,
                                                  float* __restrict__ pl1,
                                                  float* __restrict__ out,
                                                  unsigned int* __restrict__ done) {
  __shared__ float4 us4[2 * BUF];    // double-buffered staged u slabs
  __shared__ float4 vs4[2 * BUF];    // double-buffered staged v slabs
  __shared__ float4 wpf[2 * WPB];    // double-buffered W-passed {su,sv,suu,svv}

  const int tid = threadIdx.x;
  const int bx  = blockIdx.x;
  const int tw  = bx % NTW;
  const int th  = (bx / NTW) % NTH;
  const int b   = (bx / (NTW * NTH)) % BC;
  const int ch  =  bx / (NTW * NTH * BC);
  const int h0 = th * TS, w0 = tw * TS, c0 = ch * CD;
  const size_t bbase = (size_t)b * (DIMZ * PLANE);
  const int d0 = c0 - PAD, dend = c0 + CD + PAD;

  // staging decomposition: 208 threads = 26 rows x 8 float4-cols (w0-8 .. w0+23)
  const int sr  = tid >> 3, sc4 = tid & 7;
  const int sgh = h0 - PAD + sr;
  const int sgw = w0 - 8 + (sc4 << 2);
  const bool sok = (tid < 208) && ((unsigned)sgh < (unsigned)DIMY) &&
                   ((unsigned)sgw < (unsigned)DIMX);
  const bool l1own = (sr >= PAD) && (sr < PAD + TS) && (sc4 >= 2) && (sc4 < 6);
  const size_t sgoff = bbase + (size_t)sgh * DIMX + sgw;   // only used when sok

  // W-pass ownership: 104 threads = 26 rows x 4 groups of 4 outputs
  const int wr = tid >> 2, wg = tid & 3;
  // H-pass / ring ownership: thread owns (row hh, col ww); reads wpf rows hh..hh+10
  const int hbase = (tid >> 4) * WPS + (tid & 15);

  float4 ring[11];
#pragma unroll
  for (int k = 0; k < 11; ++k) ring[k] = make_float4(0.f, 0.f, 0.f, 0.f);
  float4 sums = make_float4(0.f, 0.f, 0.f, 0.f);
  float l1loc = 0.f, ssloc = 0.f;

  const float inv = 1.0f / 1331.0f;             // 1/11^3
  const float c1  = 0.01f / (4096.f * 4096.f);  // K1 / data_range^2 (faithful to ref)
  const float c2  = 0.03f / (4096.f * 4096.f);

  // --- prologue: stage slab d0 into buf0; leave slab d0+1 in regs ---
  float4 xq = make_float4(0.f, 0.f, 0.f, 0.f), yq = xq;
  if (sok && (unsigned)d0 < (unsigned)DIMZ) {
    const size_t g = sgoff + (size_t)d0 * PLANE;
    xq = *(const float4*)(X + g);
    yq = *(const float4*)(Y + g);
  }
  if (tid < 208 && (unsigned)d0 < (unsigned)DIMZ) {
    us4[sr * XS4 + sc4] = f4add(xq, yq);
    vs4[sr * XS4 + sc4] = f4sub(xq, yq);
    // d0 = c0-PAD < c0: never an L1-owned slab
  }
  xq = make_float4(0.f, 0.f, 0.f, 0.f); yq = xq;
  if (sok && (unsigned)(d0 + 1) < (unsigned)DIMZ) {
    const size_t g = sgoff + (size_t)(d0 + 1) * PLANE;
    xq = *(const float4*)(X + g);
    yq = *(const float4*)(Y + g);
  }
  __syncthreads();

  int cur = 0;                     // W-pass reads buf[cur]; stage writes buf[cur^1]
  int wp  = 0;                     // W-pass writes wpf[wp]; H reads wpf[wp]
  int ph  = (d0 + 22) % 11;        // uniform ring phase

  for (int d = d0; d < dend; ++d) {
    const bool dval = (unsigned)d < (unsigned)DIMZ;
    const int dn = d + 1;

    // --- P1a: stage slab d+1 from prefetched regs into buf[cur^1];
    //          fuse smooth-L1; issue prefetch of slab d+2 ---
    if (tid < 208) {
      if ((unsigned)dn < (unsigned)DIMZ && dn < dend) {
        const float4 u = f4add(xq, yq);
        const float4 v = f4sub(xq, yq);
        us4[(cur ^ 1) * BUF + sr * XS4 + sc4] = u;
        vs4[(cur ^ 1) * BUF + sr * XS4 + sc4] = v;
        if (dn >= c0 && dn < c0 + CD && l1own) {
          const float a0 = fabsf(v.x), a1 = fabsf(v.y);
          const float a2 = fabsf(v.z), a3 = fabsf(v.w);
          l1loc += (a0 < 1.f) ? 0.5f * a0 * a0 : a0 - 0.5f;
          l1loc += (a1 < 1.f) ? 0.5f * a1 * a1 : a1 - 0.5f;
          l1loc += (a2 < 1.f) ? 0.5f * a2 * a2 : a2 - 0.5f;
          l1loc += (a3 < 1.f) ? 0.5f * a3 * a3 : a3 - 0.5f;
        }
      }
      const int d2 = d + 2;
      if (sok && (unsigned)d2 < (unsigned)DIMZ && d2 < dend) {
        const size_t g = sgoff + (size_t)d2 * PLANE;
        xq = *(const float4*)(X + g);   // in flight across W/H of this iter
        yq = *(const float4*)(Y + g);
      } else {
        xq = make_float4(0.f, 0.f, 0.f, 0.f);
        yq = make_float4(0.f, 0.f, 0.f, 0.f);
      }
    }

    // --- P1b: W-pass of slab d from buf[cur] into wpf[wp]: 104 thr x 4 out ---
    if (dval && tid < 104) {
      const int rb = cur * BUF + wr * XS4 + wg;
      const int o  = wp * WPB + wr * WPS + (wg << 2);
      float su[4], sv[4], suu[4], svv[4];
      float t[20];
      {  // field u
        float4 q;
        q = us4[rb    ]; t[0]=q.x;  t[1]=q.y;  t[2]=q.z;  t[3]=q.w;
        q = us4[rb + 1]; t[4]=q.x;  t[5]=q.y;  t[6]=q.z;  t[7]=q.w;
        q = us4[rb + 2]; t[8]=q.x;  t[9]=q.y;  t[10]=q.z; t[11]=q.w;
        q = us4[rb + 3]; t[12]=q.x; t[13]=q.y; t[14]=q.z; t[15]=q.w;
        q = us4[rb + 4]; t[16]=q.x; t[17]=q.y; t[18]=q.z; t[19]=q.w;
        float s = 0.f, ss = 0.f;
#pragma unroll
        for (int j = 3; j <= 13; ++j) { s += t[j]; ss = fmaf(t[j], t[j], ss); }
        su[0] = s; suu[0] = ss;
#pragma unroll
        for (int k = 1; k < 4; ++k) {
          const float nw = t[13 + k], od = t[2 + k];
          s += nw - od;
          ss = fmaf(nw, nw, fmaf(-od, od, ss));
          su[k] = s; suu[k] = ss;
        }
      }
      {  // field v
        float4 q;
        q = vs4[rb    ]; t[0]=q.x;  t[1]=q.y;  t[2]=q.z;  t[3]=q.w;
        q = vs4[rb + 1]; t[4]=q.x;  t[5]=q.y;  t[6]=q.z;  t[7]=q.w;
        q = vs4[rb + 2]; t[8]=q.x;  t[9]=q.y;  t[10]=q.z; t[11]=q.w;
        q = vs4[rb + 3]; t[12]=q.x; t[13]=q.y; t[14]=q.z; t[15]=q.w;
        q = vs4[rb + 4]; t[16]=q.x; t[17]=q.y; t[18]=q.z; t[19]=q.w;
        float s = 0.f, ss = 0.f;
#pragma unroll
        for (int j = 3; j <= 13; ++j) { s += t[j]; ss = fmaf(t[j], t[j], ss); }
        sv[0] = s; svv[0] = ss;
#pragma unroll
        for (int k = 1; k < 4; ++k) {
          const float nw = t[13 + k], od = t[2 + k];
          s += nw - od;
          ss = fmaf(nw, nw, fmaf(-od, od, ss));
          sv[k] = s; svv[k] = ss;
        }
      }
#pragma unroll
      for (int k = 0; k < 4; ++k)
        wpf[o + k] = make_float4(su[k], sv[k], suu[k], svv[k]);
    }
    __syncthreads();   // B1: wpf[wp] complete; buf[cur] free for restage

    // --- P2: H-pass, all 256 threads, 1 output each -> Sv in register ---
    float4 Sv = make_float4(0.f, 0.f, 0.f, 0.f);
    if (dval) {
      const int hb = wp * WPB + hbase;
      float4 S = wpf[hb];
#pragma unroll
      for (int t = 1; t <= 10; ++t) S = f4add(S, wpf[hb + t * WPS]);
      Sv = S;
    }

    // --- D-window ring update (registers, uniform switch) ---
    switch (ph) {
      RING_CASE(0) RING_CASE(1) RING_CASE(2) RING_CASE(3) RING_CASE(4)
      RING_CASE(5) RING_CASE(6) RING_CASE(7) RING_CASE(8) RING_CASE(9)
      RING_CASE(10)
    }
    ph = (ph == 10) ? 0 : ph + 1;

    // --- SSIM for output voxel dc = d-5 (u/v algebra) ---
    if (d >= c0 + PAD) {
      const float mu_u = sums.x * inv, mu_v = sums.y * inv;
      const float Euu  = sums.z * inv, Evv  = sums.w * inv;
      const float P = mu_u * mu_u, Q = mu_v * mu_v;
      const float sgu = Euu - P, sgv = Evv - Q;
      const float num = (0.5f * (P - Q) + c1) * (0.5f * (sgu - sgv) + c2);
      const float den = (0.5f * (P + Q) + c1) * (0.5f * (sgu + sgv) + c2);
      const float ssim = num * __builtin_amdgcn_rcpf(den + 1e-8f);
      const float val  = 0.5f * (1.f - ssim);
      ssloc += fminf(fmaxf(val, 0.f), 1.f);
    }

    cur ^= 1;
    wp  ^= 1;
  }

  // --- block reduction -> per-block partials ---
#pragma unroll
  for (int off = 32; off > 0; off >>= 1) {
    ssloc += __shfl_down(ssloc, off, 64);
    l1loc += __shfl_down(l1loc, off, 64);
  }
  __syncthreads();                 // LDS compute use done; reuse us4 as scratch
  float* scr = (float*)us4;
  const int lane = tid & 63, wv = tid >> 6;
  if (lane == 0) {
    scr[wv * 2]     = ssloc;
    scr[wv * 2 + 1] = l1loc;
  }
  __syncthreads();

  __shared__ unsigned int islast;
  if (tid == 0) {
    pssim[bx] = scr[0] + scr[2] + scr[4] + scr[6];
    pl1[bx]   = scr[1] + scr[3] + scr[5] + scr[7];
    __threadfence();               // release partials (device scope, cross-XCD)
    islast = (atomicAdd(done, 1u) == (unsigned)(NBLK - 1)) ? 1u : 0u;
  }
  __syncthreads();

  // --- last block: grid reduction (same double-precision order as before) ---
  if (islast != 0u) {
    __threadfence();               // acquire all partials
    double s = 0.0, l = 0.0;
    for (int i = tid; i < NBLK; i += 256) {
      s += (double)pssim[i];
      l += (double)pl1[i];
    }
#pragma unroll
    for (int off = 32; off > 0; off >>= 1) {
      s += __shfl_down(s, off, 64);
      l += __shfl_down(l, off, 64);
    }
    double* dm = (double*)vs4;
    if (lane == 0) { dm[wv * 2] = s; dm[wv * 2 + 1] = l; }
    __syncthreads();
    if (tid == 0) {
      const double ssm = (dm[0] + dm[2] + dm[4] + dm[6]) / (double)NTOT;
      const double l1m = (dm[1] + dm[3] + dm[5] + dm[7]) / (double)NTOT;
      out[0] = (float)(0.85 * ssm + 0.15 * l1m);
      *done = 0u;                  // self-reset for graph replay
    }
  }
}

extern "C" void kernel_launch(void* const* d_in, const int* in_sizes, int n_in,
                              void* d_out, int out_size, void* d_ws, size_t ws_size,
                              hipStream_t stream) {
  const float* X = (const float*)d_in[0];
  const float* Y = (const float*)d_in[1];
  float* out = (float*)d_out;

  float* pssim = (float*)d_ws;        // NBLK floats
  float* pl1   = pssim + NBLK;        // NBLK floats
  unsigned int* done = (unsigned int*)(pl1 + NBLK);

  hipMemsetAsync(done, 0, sizeof(unsigned int), stream);  // first-launch safety
  fused_ssim<<<NBLK, 256, 0, stream>>>(X, Y, pssim, pl1, out, done);
}

// Round 12
// 165.012 us; speedup vs baseline: 1.0353x; 1.0353x over previous
//
#include <hip/hip_runtime.h>

// Shape fixed by reference: (2,1,160,160,160) fp32, window 11, zero-pad box filter.
// Fields reduced via u=x+y, v=x-y: box{u, v, u^2, v^2} packed in one float4.
// v6 = v3 kernel body (best measured: 70.3us; 104x4 W-pass, 64x4 H-pass via Sb,
//      2 barriers/iter, double-buffered us4/vs4, CD=32)
//    + v5's validated fused final reduction (atomic counter + device fences,
//      identical double-precision order -> bit-identical; saves ~12us dispatch
//      overhead, measured v4->v5).
// Law (x2 confirmed, v1 & v5): never widen a phase if it raises total b128
// wave-ops -- sliding-window reuse beats thread-width in this kernel.
// (Resubmission x5: rounds 7-11 failed on GPU acquisition, no data.)
#define DIMX 160
#define DIMY 160
#define DIMZ 160
#define BC   2
#define NTOT (BC * DIMZ * DIMY * DIMX)   // 8,192,000
#define PLANE (DIMY * DIMX)
#define PAD  5
#define TS   16                  // tile size in H and W
#define HS   26                  // TS + 2*PAD rows
#define XS4  10                  // stage row stride in float4 (8 used + 2 pad)
#define BUF  (HS * XS4)          // one u/v slab buffer in float4 (260)
#define WPS  17                  // wpf row stride in float4 (breaks bank aliasing)
#define CD   32                  // D-chunk per block
#define NCH  (DIMZ / CD)         // 5
#define NTH  (DIMY / TS)         // 10
#define NTW  (DIMX / TS)         // 10
#define NBLK (NCH * BC * NTH * NTW)  // 1000 blocks

static_assert(NTOT == 8192000, "size mismatch");
static_assert(NCH * CD == DIMZ, "CD must divide DIMZ");

__device__ __forceinline__ float4 f4add(float4 a, float4 b) {
  return make_float4(a.x + b.x, a.y + b.y, a.z + b.z, a.w + b.w);
}
__device__ __forceinline__ float4 f4sub(float4 a, float4 b) {
  return make_float4(a.x - b.x, a.y - b.y, a.z - b.z, a.w - b.w);
}

// Ring slot update with compile-time index K (keeps ring[] in VGPRs).
#define RING_CASE(K) case K: {                 \
    sums = f4add(sums, f4sub(Sv, ring[K]));    \
    ring[K] = Sv;                              \
  } break;

__global__ __launch_bounds__(256) void fused_ssim(const float* __restrict__ X,
                                                  const float* __restrict__ Y,
                                                  float* __restrict__ pssim,
                                                  float* __restrict__ pl1,
                                                  float* __restrict__ out,
                                                  unsigned int* __restrict__ done) {
  __shared__ float4 us4[2 * BUF];    // double-buffered staged u slabs
  __shared__ float4 vs4[2 * BUF];    // double-buffered staged v slabs
  __shared__ float4 wpf[HS * WPS];   // W-passed {su,sv,suu,svv}, stride 17
  __shared__ float4 Sb[TS * TS];     // H-passed per-voxel field vector

  const int tid = threadIdx.x;
  const int bx  = blockIdx.x;
  const int tw  = bx % NTW;
  const int th  = (bx / NTW) % NTH;
  const int b   = (bx / (NTW * NTH)) % BC;
  const int ch  =  bx / (NTW * NTH * BC);
  const int h0 = th * TS, w0 = tw * TS, c0 = ch * CD;
  const size_t bbase = (size_t)b * (DIMZ * PLANE);
  const int d0 = c0 - PAD, dend = c0 + CD + PAD;

  // staging decomposition: 208 threads = 26 rows x 8 float4-cols (w0-8 .. w0+23)
  const int sr  = tid >> 3, sc4 = tid & 7;
  const int sgh = h0 - PAD + sr;
  const int sgw = w0 - 8 + (sc4 << 2);
  const bool sok = (tid < 208) && ((unsigned)sgh < (unsigned)DIMY) &&
                   ((unsigned)sgw < (unsigned)DIMX);
  const bool l1own = (sr >= PAD) && (sr < PAD + TS) && (sc4 >= 2) && (sc4 < 6);
  const size_t sgoff = bbase + (size_t)sgh * DIMX + sgw;   // only used when sok

  float4 ring[11];
#pragma unroll
  for (int k = 0; k < 11; ++k) ring[k] = make_float4(0.f, 0.f, 0.f, 0.f);
  float4 sums = make_float4(0.f, 0.f, 0.f, 0.f);
  float l1loc = 0.f, ssloc = 0.f;

  const float inv = 1.0f / 1331.0f;             // 1/11^3
  const float c1  = 0.01f / (4096.f * 4096.f);  // K1 / data_range^2 (faithful to ref)
  const float c2  = 0.03f / (4096.f * 4096.f);

  // --- prologue: stage slab d0 into buf0; leave slab d0+1 in regs ---
  float4 xq = make_float4(0.f, 0.f, 0.f, 0.f), yq = xq;
  if (sok && (unsigned)d0 < (unsigned)DIMZ) {
    const size_t g = sgoff + (size_t)d0 * PLANE;
    xq = *(const float4*)(X + g);
    yq = *(const float4*)(Y + g);
  }
  if (tid < 208 && (unsigned)d0 < (unsigned)DIMZ) {
    us4[sr * XS4 + sc4] = f4add(xq, yq);
    vs4[sr * XS4 + sc4] = f4sub(xq, yq);
    // d0 = c0-PAD < c0: never an L1-owned slab
  }
  xq = make_float4(0.f, 0.f, 0.f, 0.f); yq = xq;
  if (sok && (unsigned)(d0 + 1) < (unsigned)DIMZ) {
    const size_t g = sgoff + (size_t)(d0 + 1) * PLANE;
    xq = *(const float4*)(X + g);
    yq = *(const float4*)(Y + g);
  }
  __syncthreads();

  int cur = 0;                     // W-pass reads buf[cur]; stage writes buf[cur^1]
  int ph = (d0 + 22) % 11;         // uniform ring phase

  for (int d = d0; d < dend; ++d) {
    const bool dval = (unsigned)d < (unsigned)DIMZ;
    const int dn = d + 1;

    // --- P1a: stage slab d+1 from prefetched regs into buf[cur^1];
    //          fuse smooth-L1; issue prefetch of slab d+2 ---
    if (tid < 208) {
      if ((unsigned)dn < (unsigned)DIMZ && dn < dend) {
        const float4 u = f4add(xq, yq);
        const float4 v = f4sub(xq, yq);
        us4[(cur ^ 1) * BUF + sr * XS4 + sc4] = u;
        vs4[(cur ^ 1) * BUF + sr * XS4 + sc4] = v;
        if (dn >= c0 && dn < c0 + CD && l1own) {
          const float a0 = fabsf(v.x), a1 = fabsf(v.y);
          const float a2 = fabsf(v.z), a3 = fabsf(v.w);
          l1loc += (a0 < 1.f) ? 0.5f * a0 * a0 : a0 - 0.5f;
          l1loc += (a1 < 1.f) ? 0.5f * a1 * a1 : a1 - 0.5f;
          l1loc += (a2 < 1.f) ? 0.5f * a2 * a2 : a2 - 0.5f;
          l1loc += (a3 < 1.f) ? 0.5f * a3 * a3 : a3 - 0.5f;
        }
      }
      const int d2 = d + 2;
      if (sok && (unsigned)d2 < (unsigned)DIMZ && d2 < dend) {
        const size_t g = sgoff + (size_t)d2 * PLANE;
        xq = *(const float4*)(X + g);   // in flight across W/H/ring of this iter
        yq = *(const float4*)(Y + g);
      } else {
        xq = make_float4(0.f, 0.f, 0.f, 0.f);
        yq = make_float4(0.f, 0.f, 0.f, 0.f);
      }
    }

    // --- P1b: W-pass of slab d from buf[cur]: 104 threads x 4 outputs ---
    if (dval && tid < 104) {
      const int wr = tid >> 2, wg = tid & 3;
      const int rb = cur * BUF + wr * XS4 + wg;
      const int o  = wr * WPS + (wg << 2);
      float su[4], sv[4], suu[4], svv[4];
      float t[20];
      {  // field u
        float4 q;
        q = us4[rb    ]; t[0]=q.x;  t[1]=q.y;  t[2]=q.z;  t[3]=q.w;
        q = us4[rb + 1]; t[4]=q.x;  t[5]=q.y;  t[6]=q.z;  t[7]=q.w;
        q = us4[rb + 2]; t[8]=q.x;  t[9]=q.y;  t[10]=q.z; t[11]=q.w;
        q = us4[rb + 3]; t[12]=q.x; t[13]=q.y; t[14]=q.z; t[15]=q.w;
        q = us4[rb + 4]; t[16]=q.x; t[17]=q.y; t[18]=q.z; t[19]=q.w;
        float s = 0.f, ss = 0.f;
#pragma unroll
        for (int j = 3; j <= 13; ++j) { s += t[j]; ss = fmaf(t[j], t[j], ss); }
        su[0] = s; suu[0] = ss;
#pragma unroll
        for (int k = 1; k < 4; ++k) {
          const float nw = t[13 + k], od = t[2 + k];
          s += nw - od;
          ss = fmaf(nw, nw, fmaf(-od, od, ss));
          su[k] = s; suu[k] = ss;
        }
      }
      {  // field v
        float4 q;
        q = vs4[rb    ]; t[0]=q.x;  t[1]=q.y;  t[2]=q.z;  t[3]=q.w;
        q = vs4[rb + 1]; t[4]=q.x;  t[5]=q.y;  t[6]=q.z;  t[7]=q.w;
        q = vs4[rb + 2]; t[8]=q.x;  t[9]=q.y;  t[10]=q.z; t[11]=q.w;
        q = vs4[rb + 3]; t[12]=q.x; t[13]=q.y; t[14]=q.z; t[15]=q.w;
        q = vs4[rb + 4]; t[16]=q.x; t[17]=q.y; t[18]=q.z; t[19]=q.w;
        float s = 0.f, ss = 0.f;
#pragma unroll
        for (int j = 3; j <= 13; ++j) { s += t[j]; ss = fmaf(t[j], t[j], ss); }
        sv[0] = s; svv[0] = ss;
#pragma unroll
        for (int k = 1; k < 4; ++k) {
          const float nw = t[13 + k], od = t[2 + k];
          s += nw - od;
          ss = fmaf(nw, nw, fmaf(-od, od, ss));
          sv[k] = s; svv[k] = ss;
        }
      }
#pragma unroll
      for (int k = 0; k < 4; ++k)
        wpf[o + k] = make_float4(su[k], sv[k], suu[k], svv[k]);
    }
    __syncthreads();   // B1: wpf complete

    // --- P2: H-pass: 64 threads x 4 sliding outputs ---
    if (dval && tid < 64) {
      const int g = tid >> 4, w = tid & 15;
      const int base = (g << 2) * WPS + w;
      const float4 T0 = wpf[base];
      const float4 T1 = wpf[base + WPS];
      const float4 T2 = wpf[base + 2 * WPS];
      float4 S = f4add(f4add(T0, T1), T2);
#pragma unroll
      for (int t = 3; t <= 10; ++t) S = f4add(S, wpf[base + t * WPS]);
      Sb[((g << 2) + 0) * TS + w] = S;
      S = f4sub(f4add(S, wpf[base + 11 * WPS]), T0);
      Sb[((g << 2) + 1) * TS + w] = S;
      S = f4sub(f4add(S, wpf[base + 12 * WPS]), T1);
      Sb[((g << 2) + 2) * TS + w] = S;
      S = f4sub(f4add(S, wpf[base + 13 * WPS]), T2);
      Sb[((g << 2) + 3) * TS + w] = S;
    }
    __syncthreads();   // B2: Sb complete

    // --- P3: redistribute, D-window ring update (registers, uniform switch) ---
    float4 Sv = make_float4(0.f, 0.f, 0.f, 0.f);
    if (dval) Sv = Sb[tid];
    switch (ph) {
      RING_CASE(0) RING_CASE(1) RING_CASE(2) RING_CASE(3) RING_CASE(4)
      RING_CASE(5) RING_CASE(6) RING_CASE(7) RING_CASE(8) RING_CASE(9)
      RING_CASE(10)
    }
    ph = (ph == 10) ? 0 : ph + 1;

    // --- SSIM for output voxel dc = d-5 (u/v algebra) ---
    if (d >= c0 + PAD) {
      const float mu_u = sums.x * inv, mu_v = sums.y * inv;
      const float Euu  = sums.z * inv, Evv  = sums.w * inv;
      const float P = mu_u * mu_u, Q = mu_v * mu_v;
      const float sgu = Euu - P, sgv = Evv - Q;
      const float num = (0.5f * (P - Q) + c1) * (0.5f * (sgu - sgv) + c2);
      const float den = (0.5f * (P + Q) + c1) * (0.5f * (sgu + sgv) + c2);
      const float ssim = num * __builtin_amdgcn_rcpf(den + 1e-8f);
      const float val  = 0.5f * (1.f - ssim);
      ssloc += fminf(fmaxf(val, 0.f), 1.f);
    }

    cur ^= 1;
  }

  // --- block reduction -> per-block partials ---
#pragma unroll
  for (int off = 32; off > 0; off >>= 1) {
    ssloc += __shfl_down(ssloc, off, 64);
    l1loc += __shfl_down(l1loc, off, 64);
  }
  __syncthreads();                 // LDS compute use done; reuse us4 as scratch
  float* scr = (float*)us4;
  const int lane = tid & 63, wv = tid >> 6;
  if (lane == 0) {
    scr[wv * 2]     = ssloc;
    scr[wv * 2 + 1] = l1loc;
  }
  __syncthreads();

  __shared__ unsigned int islast;
  if (tid == 0) {
    pssim[bx] = scr[0] + scr[2] + scr[4] + scr[6];
    pl1[bx]   = scr[1] + scr[3] + scr[5] + scr[7];
    __threadfence();               // release partials (device scope, cross-XCD)
    islast = (atomicAdd(done, 1u) == (unsigned)(NBLK - 1)) ? 1u : 0u;
  }
  __syncthreads();

  // --- last block: grid reduction (same double-precision order as the old
  //     final_reduce kernel -> bit-identical result) ---
  if (islast != 0u) {
    __threadfence();               // acquire all partials
    double s = 0.0, l = 0.0;
    for (int i = tid; i < NBLK; i += 256) {
      s += (double)pssim[i];
      l += (double)pl1[i];
    }
#pragma unroll
    for (int off = 32; off > 0; off >>= 1) {
      s += __shfl_down(s, off, 64);
      l += __shfl_down(l, off, 64);
    }
    double* dm = (double*)vs4;
    if (lane == 0) { dm[wv * 2] = s; dm[wv * 2 + 1] = l; }
    __syncthreads();
    if (tid == 0) {
      const double ssm = (dm[0] + dm[2] + dm[4] + dm[6]) / (double)NTOT;
      const double l1m = (dm[1] + dm[3] + dm[5] + dm[7]) / (double)NTOT;
      out[0] = (float)(0.85 * ssm + 0.15 * l1m);
      *done = 0u;                  // self-reset for graph replay
    }
  }
}

extern "C" void kernel_launch(void* const* d_in, const int* in_sizes, int n_in,
                              void* d_out, int out_size, void* d_ws, size_t ws_size,
                              hipStream_t stream) {
  const float* X = (const float*)d_in[0];
  const float* Y = (const float*)d_in[1];
  float* out = (float*)d_out;

  float* pssim = (float*)d_ws;        // NBLK floats
  float* pl1   = pssim + NBLK;        // NBLK floats
  unsigned int* done = (unsigned int*)(pl1 + NBLK);

  hipMemsetAsync(done, 0, sizeof(unsigned int), stream);  // first-launch safety
  fused_ssim<<<NBLK, 256, 0, stream>>>(X, Y, pssim, pl1, out, done);
}

// Round 16
// 151.634 us; speedup vs baseline: 1.1267x; 1.0882x over previous
//
#include <hip/hip_runtime.h>

// Shape fixed by reference: (2,1,160,160,160) fp32, window 11, zero-pad box filter.
// Fields reduced via u=x+y, v=x-y: box{u, v, u^2, v^2} packed in one float4.
// v7 = v3 body verbatim (best kernel: 70.3us) + CD 32->40 (halo 1.31x -> 1.25x)
//      + REVERT to two dispatches (v6 measured: fused atomic tail costs +24us
//        in-kernel from per-block device-scope threadfence L2 writebacks,
//        WRITE_SIZE +31MB; dispatch-overhead saving was noise).
// Bank-conflict note (v4/v6 analysis): all LDS patterns are 8-lanes-per-quad
// optimal for b128; SQ_LDS_BANK_CONFLICT ~7.4e6 is inherent wide-op counting,
// not fixable conflict. Do not chase it.
// (Resubmission x3: rounds 13/14 GPU-acquisition failures, round 15 container
//  failure; no kernel data since round 12.)
#define DIMX 160
#define DIMY 160
#define DIMZ 160
#define BC   2
#define NTOT (BC * DIMZ * DIMY * DIMX)   // 8,192,000
#define PLANE (DIMY * DIMX)
#define PAD  5
#define TS   16                  // tile size in H and W
#define HS   26                  // TS + 2*PAD rows
#define XS4  10                  // stage row stride in float4 (8 used + 2 pad)
#define BUF  (HS * XS4)          // one u/v slab buffer in float4 (260)
#define WPS  17                  // wpf row stride in float4 (breaks bank aliasing)
#define CD   40                  // D-chunk per block
#define NCH  (DIMZ / CD)         // 4
#define NTH  (DIMY / TS)         // 10
#define NTW  (DIMX / TS)         // 10
#define NBLK (NCH * BC * NTH * NTW)  // 800 blocks

static_assert(NTOT == 8192000, "size mismatch");
static_assert(NCH * CD == DIMZ, "CD must divide DIMZ");

__device__ __forceinline__ float4 f4add(float4 a, float4 b) {
  return make_float4(a.x + b.x, a.y + b.y, a.z + b.z, a.w + b.w);
}
__device__ __forceinline__ float4 f4sub(float4 a, float4 b) {
  return make_float4(a.x - b.x, a.y - b.y, a.z - b.z, a.w - b.w);
}

// Ring slot update with compile-time index K (keeps ring[] in VGPRs).
#define RING_CASE(K) case K: {                 \
    sums = f4add(sums, f4sub(Sv, ring[K]));    \
    ring[K] = Sv;                              \
  } break;

__global__ __launch_bounds__(256) void fused_ssim(const float* __restrict__ X,
                                                  const float* __restrict__ Y,
                                                  float* __restrict__ pssim,
                                                  float* __restrict__ pl1) {
  __shared__ float4 us4[2 * BUF];    // double-buffered staged u slabs
  __shared__ float4 vs4[2 * BUF];    // double-buffered staged v slabs
  __shared__ float4 wpf[HS * WPS];   // W-passed {su,sv,suu,svv}, stride 17
  __shared__ float4 Sb[TS * TS];     // H-passed per-voxel field vector

  const int tid = threadIdx.x;
  const int bx  = blockIdx.x;
  const int tw  = bx % NTW;
  const int th  = (bx / NTW) % NTH;
  const int b   = (bx / (NTW * NTH)) % BC;
  const int ch  =  bx / (NTW * NTH * BC);
  const int h0 = th * TS, w0 = tw * TS, c0 = ch * CD;
  const size_t bbase = (size_t)b * (DIMZ * PLANE);
  const int d0 = c0 - PAD, dend = c0 + CD + PAD;

  // staging decomposition: 208 threads = 26 rows x 8 float4-cols (w0-8 .. w0+23)
  const int sr  = tid >> 3, sc4 = tid & 7;
  const int sgh = h0 - PAD + sr;
  const int sgw = w0 - 8 + (sc4 << 2);
  const bool sok = (tid < 208) && ((unsigned)sgh < (unsigned)DIMY) &&
                   ((unsigned)sgw < (unsigned)DIMX);
  const bool l1own = (sr >= PAD) && (sr < PAD + TS) && (sc4 >= 2) && (sc4 < 6);
  const size_t sgoff = bbase + (size_t)sgh * DIMX + sgw;   // only used when sok

  float4 ring[11];
#pragma unroll
  for (int k = 0; k < 11; ++k) ring[k] = make_float4(0.f, 0.f, 0.f, 0.f);
  float4 sums = make_float4(0.f, 0.f, 0.f, 0.f);
  float l1loc = 0.f, ssloc = 0.f;

  const float inv = 1.0f / 1331.0f;             // 1/11^3
  const float c1  = 0.01f / (4096.f * 4096.f);  // K1 / data_range^2 (faithful to ref)
  const float c2  = 0.03f / (4096.f * 4096.f);

  // --- prologue: stage slab d0 into buf0; leave slab d0+1 in regs ---
  float4 xq = make_float4(0.f, 0.f, 0.f, 0.f), yq = xq;
  if (sok && (unsigned)d0 < (unsigned)DIMZ) {
    const size_t g = sgoff + (size_t)d0 * PLANE;
    xq = *(const float4*)(X + g);
    yq = *(const float4*)(Y + g);
  }
  if (tid < 208 && (unsigned)d0 < (unsigned)DIMZ) {
    us4[sr * XS4 + sc4] = f4add(xq, yq);
    vs4[sr * XS4 + sc4] = f4sub(xq, yq);
    // d0 = c0-PAD < c0: never an L1-owned slab
  }
  xq = make_float4(0.f, 0.f, 0.f, 0.f); yq = xq;
  if (sok && (unsigned)(d0 + 1) < (unsigned)DIMZ) {
    const size_t g = sgoff + (size_t)(d0 + 1) * PLANE;
    xq = *(const float4*)(X + g);
    yq = *(const float4*)(Y + g);
  }
  __syncthreads();

  int cur = 0;                     // W-pass reads buf[cur]; stage writes buf[cur^1]
  int ph = (d0 + 22) % 11;         // uniform ring phase

  for (int d = d0; d < dend; ++d) {
    const bool dval = (unsigned)d < (unsigned)DIMZ;
    const int dn = d + 1;

    // --- P1a: stage slab d+1 from prefetched regs into buf[cur^1];
    //          fuse smooth-L1; issue prefetch of slab d+2 ---
    if (tid < 208) {
      if ((unsigned)dn < (unsigned)DIMZ && dn < dend) {
        const float4 u = f4add(xq, yq);
        const float4 v = f4sub(xq, yq);
        us4[(cur ^ 1) * BUF + sr * XS4 + sc4] = u;
        vs4[(cur ^ 1) * BUF + sr * XS4 + sc4] = v;
        if (dn >= c0 && dn < c0 + CD && l1own) {
          const float a0 = fabsf(v.x), a1 = fabsf(v.y);
          const float a2 = fabsf(v.z), a3 = fabsf(v.w);
          l1loc += (a0 < 1.f) ? 0.5f * a0 * a0 : a0 - 0.5f;
          l1loc += (a1 < 1.f) ? 0.5f * a1 * a1 : a1 - 0.5f;
          l1loc += (a2 < 1.f) ? 0.5f * a2 * a2 : a2 - 0.5f;
          l1loc += (a3 < 1.f) ? 0.5f * a3 * a3 : a3 - 0.5f;
        }
      }
      const int d2 = d + 2;
      if (sok && (unsigned)d2 < (unsigned)DIMZ && d2 < dend) {
        const size_t g = sgoff + (size_t)d2 * PLANE;
        xq = *(const float4*)(X + g);   // in flight across W/H/ring of this iter
        yq = *(const float4*)(Y + g);
      } else {
        xq = make_float4(0.f, 0.f, 0.f, 0.f);
        yq = make_float4(0.f, 0.f, 0.f, 0.f);
      }
    }

    // --- P1b: W-pass of slab d from buf[cur]: 104 threads x 4 outputs ---
    if (dval && tid < 104) {
      const int wr = tid >> 2, wg = tid & 3;
      const int rb = cur * BUF + wr * XS4 + wg;
      const int o  = wr * WPS + (wg << 2);
      float su[4], sv[4], suu[4], svv[4];
      float t[20];
      {  // field u
        float4 q;
        q = us4[rb    ]; t[0]=q.x;  t[1]=q.y;  t[2]=q.z;  t[3]=q.w;
        q = us4[rb + 1]; t[4]=q.x;  t[5]=q.y;  t[6]=q.z;  t[7]=q.w;
        q = us4[rb + 2]; t[8]=q.x;  t[9]=q.y;  t[10]=q.z; t[11]=q.w;
        q = us4[rb + 3]; t[12]=q.x; t[13]=q.y; t[14]=q.z; t[15]=q.w;
        q = us4[rb + 4]; t[16]=q.x; t[17]=q.y; t[18]=q.z; t[19]=q.w;
        float s = 0.f, ss = 0.f;
#pragma unroll
        for (int j = 3; j <= 13; ++j) { s += t[j]; ss = fmaf(t[j], t[j], ss); }
        su[0] = s; suu[0] = ss;
#pragma unroll
        for (int k = 1; k < 4; ++k) {
          const float nw = t[13 + k], od = t[2 + k];
          s += nw - od;
          ss = fmaf(nw, nw, fmaf(-od, od, ss));
          su[k] = s; suu[k] = ss;
        }
      }
      {  // field v
        float4 q;
        q = vs4[rb    ]; t[0]=q.x;  t[1]=q.y;  t[2]=q.z;  t[3]=q.w;
        q = vs4[rb + 1]; t[4]=q.x;  t[5]=q.y;  t[6]=q.z;  t[7]=q.w;
        q = vs4[rb + 2]; t[8]=q.x;  t[9]=q.y;  t[10]=q.z; t[11]=q.w;
        q = vs4[rb + 3]; t[12]=q.x; t[13]=q.y; t[14]=q.z; t[15]=q.w;
        q = vs4[rb + 4]; t[16]=q.x; t[17]=q.y; t[18]=q.z; t[19]=q.w;
        float s = 0.f, ss = 0.f;
#pragma unroll
        for (int j = 3; j <= 13; ++j) { s += t[j]; ss = fmaf(t[j], t[j], ss); }
        sv[0] = s; svv[0] = ss;
#pragma unroll
        for (int k = 1; k < 4; ++k) {
          const float nw = t[13 + k], od = t[2 + k];
          s += nw - od;
          ss = fmaf(nw, nw, fmaf(-od, od, ss));
          sv[k] = s; svv[k] = ss;
        }
      }
#pragma unroll
      for (int k = 0; k < 4; ++k)
        wpf[o + k] = make_float4(su[k], sv[k], suu[k], svv[k]);
    }
    __syncthreads();   // B1: wpf complete

    // --- P2: H-pass: 64 threads x 4 sliding outputs ---
    if (dval && tid < 64) {
      const int g = tid >> 4, w = tid & 15;
      const int base = (g << 2) * WPS + w;
      const float4 T0 = wpf[base];
      const float4 T1 = wpf[base + WPS];
      const float4 T2 = wpf[base + 2 * WPS];
      float4 S = f4add(f4add(T0, T1), T2);
#pragma unroll
      for (int t = 3; t <= 10; ++t) S = f4add(S, wpf[base + t * WPS]);
      Sb[((g << 2) + 0) * TS + w] = S;
      S = f4sub(f4add(S, wpf[base + 11 * WPS]), T0);
      Sb[((g << 2) + 1) * TS + w] = S;
      S = f4sub(f4add(S, wpf[base + 12 * WPS]), T1);
      Sb[((g << 2) + 2) * TS + w] = S;
      S = f4sub(f4add(S, wpf[base + 13 * WPS]), T2);
      Sb[((g << 2) + 3) * TS + w] = S;
    }
    __syncthreads();   // B2: Sb complete

    // --- P3: redistribute, D-window ring update (registers, uniform switch) ---
    float4 Sv = make_float4(0.f, 0.f, 0.f, 0.f);
    if (dval) Sv = Sb[tid];
    switch (ph) {
      RING_CASE(0) RING_CASE(1) RING_CASE(2) RING_CASE(3) RING_CASE(4)
      RING_CASE(5) RING_CASE(6) RING_CASE(7) RING_CASE(8) RING_CASE(9)
      RING_CASE(10)
    }
    ph = (ph == 10) ? 0 : ph + 1;

    // --- SSIM for output voxel dc = d-5 (u/v algebra) ---
    if (d >= c0 + PAD) {
      const float mu_u = sums.x * inv, mu_v = sums.y * inv;
      const float Euu  = sums.z * inv, Evv  = sums.w * inv;
      const float P = mu_u * mu_u, Q = mu_v * mu_v;
      const float sgu = Euu - P, sgv = Evv - Q;
      const float num = (0.5f * (P - Q) + c1) * (0.5f * (sgu - sgv) + c2);
      const float den = (0.5f * (P + Q) + c1) * (0.5f * (sgu + sgv) + c2);
      const float ssim = num * __builtin_amdgcn_rcpf(den + 1e-8f);
      const float val  = 0.5f * (1.f - ssim);
      ssloc += fminf(fmaxf(val, 0.f), 1.f);
    }

    cur ^= 1;
  }

  // --- block reduction -> per-block partials ---
#pragma unroll
  for (int off = 32; off > 0; off >>= 1) {
    ssloc += __shfl_down(ssloc, off, 64);
    l1loc += __shfl_down(l1loc, off, 64);
  }
  __syncthreads();                 // LDS compute use done; reuse us4 as scratch
  float* scr = (float*)us4;
  const int lane = tid & 63, wv = tid >> 6;
  if (lane == 0) {
    scr[wv * 2]     = ssloc;
    scr[wv * 2 + 1] = l1loc;
  }
  __syncthreads();
  if (tid == 0) {
    pssim[bx] = scr[0] + scr[2] + scr[4] + scr[6];
    pl1[bx]   = scr[1] + scr[3] + scr[5] + scr[7];
  }
}

// Final: reduce 800 + 800 partials in double, emit scalar loss.
__global__ __launch_bounds__(256) void final_reduce(const float* __restrict__ pssim,
                                                    const float* __restrict__ pl1,
                                                    float* __restrict__ out) {
  double s = 0.0, l = 0.0;
  for (int i = threadIdx.x; i < NBLK; i += 256) {
    s += (double)pssim[i];
    l += (double)pl1[i];
  }
#pragma unroll
  for (int off = 32; off > 0; off >>= 1) {
    s += __shfl_down(s, off, 64);
    l += __shfl_down(l, off, 64);
  }
  __shared__ double sm[8];
  const int lane = threadIdx.x & 63, wv = threadIdx.x >> 6;
  if (lane == 0) { sm[wv * 2] = s; sm[wv * 2 + 1] = l; }
  __syncthreads();
  if (threadIdx.x == 0) {
    const double ssm = (sm[0] + sm[2] + sm[4] + sm[6]) / (double)NTOT;
    const double l1m = (sm[1] + sm[3] + sm[5] + sm[7]) / (double)NTOT;
    out[0] = (float)(0.85 * ssm + 0.15 * l1m);
  }
}

extern "C" void kernel_launch(void* const* d_in, const int* in_sizes, int n_in,
                              void* d_out, int out_size, void* d_ws, size_t ws_size,
                              hipStream_t stream) {
  const float* X = (const float*)d_in[0];
  const float* Y = (const float*)d_in[1];
  float* out = (float*)d_out;

  float* pssim = (float*)d_ws;        // NBLK floats
  float* pl1   = pssim + NBLK;        // NBLK floats

  fused_ssim<<<NBLK, 256, 0, stream>>>(X, Y, pssim, pl1);
  final_reduce<<<1, 256, 0, stream>>>(pssim, pl1, out);
}

// Round 19
// 143.530 us; speedup vs baseline: 1.1903x; 1.0565x over previous
//
#include <hip/hip_runtime.h>

// Shape fixed by reference: (2,1,160,160,160) fp32, window 11, zero-pad box filter.
// Fields reduced via u=x+y, v=x-y: box{u, v, u^2, v^2} packed in one float4.
// v8 = v3 body (CD=32 confirmed optimal: imbalance model time ~ maxblk/CU x iters;
//      CD40 regressed 70.3->77.5us as model predicts) with ONE barrier/iter:
//      H-pass output consumed one iteration later (P3 reads Sb[pp^1]); wpf and Sb
//      double-buffered so every write->read / read->rewrite pair crosses >=1
//      barrier. Phase widths and LDS patterns unchanged (reuse law respected).
//      LDS 28160 -> 38976B -> cap 4 blk/CU = measured max residency.
// Separate final_reduce kept (v6: fused atomic tail costs +24us in-kernel).
// (Resubmission x2: rounds 17/18 failed on GPU acquisition, no data.)
#define DIMX 160
#define DIMY 160
#define DIMZ 160
#define BC   2
#define NTOT (BC * DIMZ * DIMY * DIMX)   // 8,192,000
#define PLANE (DIMY * DIMX)
#define PAD  5
#define TS   16                  // tile size in H and W
#define HS   26                  // TS + 2*PAD rows
#define XS4  10                  // stage row stride in float4 (8 used + 2 pad)
#define BUF  (HS * XS4)          // one u/v slab buffer in float4 (260)
#define WPS  17                  // wpf row stride in float4 (breaks bank aliasing)
#define WPB  (HS * WPS)          // one wpf buffer in float4 (442)
#define CD   32                  // D-chunk per block (optimal per imbalance model)
#define NCH  (DIMZ / CD)         // 5
#define NTH  (DIMY / TS)         // 10
#define NTW  (DIMX / TS)         // 10
#define NBLK (NCH * BC * NTH * NTW)  // 1000 blocks

static_assert(NTOT == 8192000, "size mismatch");
static_assert(NCH * CD == DIMZ, "CD must divide DIMZ");

__device__ __forceinline__ float4 f4add(float4 a, float4 b) {
  return make_float4(a.x + b.x, a.y + b.y, a.z + b.z, a.w + b.w);
}
__device__ __forceinline__ float4 f4sub(float4 a, float4 b) {
  return make_float4(a.x - b.x, a.y - b.y, a.z - b.z, a.w - b.w);
}

// Ring slot update with compile-time index K (keeps ring[] in VGPRs).
#define RING_CASE(K) case K: {                 \
    sums = f4add(sums, f4sub(Sv, ring[K]));    \
    ring[K] = Sv;                              \
  } break;

__global__ __launch_bounds__(256) void fused_ssim(const float* __restrict__ X,
                                                  const float* __restrict__ Y,
                                                  float* __restrict__ pssim,
                                                  float* __restrict__ pl1) {
  __shared__ float4 us4[2 * BUF];     // double-buffered staged u slabs
  __shared__ float4 vs4[2 * BUF];     // double-buffered staged v slabs
  __shared__ float4 wpf[2 * WPB];     // double-buffered W-passed fields
  __shared__ float4 Sb[2 * TS * TS];  // double-buffered H-passed per-voxel vec

  const int tid = threadIdx.x;
  const int bx  = blockIdx.x;
  const int tw  = bx % NTW;
  const int th  = (bx / NTW) % NTH;
  const int b   = (bx / (NTW * NTH)) % BC;
  const int ch  =  bx / (NTW * NTH * BC);
  const int h0 = th * TS, w0 = tw * TS, c0 = ch * CD;
  const size_t bbase = (size_t)b * (DIMZ * PLANE);
  const int d0 = c0 - PAD, dend = c0 + CD + PAD;

  // staging decomposition: 208 threads = 26 rows x 8 float4-cols (w0-8 .. w0+23)
  const int sr  = tid >> 3, sc4 = tid & 7;
  const int sgh = h0 - PAD + sr;
  const int sgw = w0 - 8 + (sc4 << 2);
  const bool sok = (tid < 208) && ((unsigned)sgh < (unsigned)DIMY) &&
                   ((unsigned)sgw < (unsigned)DIMX);
  const bool l1own = (sr >= PAD) && (sr < PAD + TS) && (sc4 >= 2) && (sc4 < 6);
  const size_t sgoff = bbase + (size_t)sgh * DIMX + sgw;   // only used when sok

  float4 ring[11];
#pragma unroll
  for (int k = 0; k < 11; ++k) ring[k] = make_float4(0.f, 0.f, 0.f, 0.f);
  float4 sums = make_float4(0.f, 0.f, 0.f, 0.f);
  float l1loc = 0.f, ssloc = 0.f;

  const float inv = 1.0f / 1331.0f;             // 1/11^3
  const float c1  = 0.01f / (4096.f * 4096.f);  // K1 / data_range^2 (faithful to ref)
  const float c2  = 0.03f / (4096.f * 4096.f);

  // --- prologue: stage slab d0 into buf0; leave slab d0+1 in regs ---
  float4 xq = make_float4(0.f, 0.f, 0.f, 0.f), yq = xq;
  if (sok && (unsigned)d0 < (unsigned)DIMZ) {
    const size_t g = sgoff + (size_t)d0 * PLANE;
    xq = *(const float4*)(X + g);
    yq = *(const float4*)(Y + g);
  }
  if (tid < 208 && (unsigned)d0 < (unsigned)DIMZ) {
    us4[sr * XS4 + sc4] = f4add(xq, yq);
    vs4[sr * XS4 + sc4] = f4sub(xq, yq);
    // d0 = c0-PAD < c0: never an L1-owned slab
  }
  xq = make_float4(0.f, 0.f, 0.f, 0.f); yq = xq;
  if (sok && (unsigned)(d0 + 1) < (unsigned)DIMZ) {
    const size_t g = sgoff + (size_t)(d0 + 1) * PLANE;
    xq = *(const float4*)(X + g);
    yq = *(const float4*)(Y + g);
  }
  __syncthreads();

  int cur = 0;                   // W reads buf[cur]; stage writes buf[cur^1]
  int pp  = 0;                   // W/H write wpf[pp]/Sb[pp]; P3 reads Sb[pp^1]
  int ph  = (d0 + 21) % 11;      // ring phase for slab d-1 (pipelined)

  // 43 iterations: stage/W/H cover slabs d0..dend-1; P3 covers d0-1..dend-1.
  for (int d = d0; d <= dend; ++d) {
    const bool dval = ((unsigned)d < (unsigned)DIMZ) && (d < dend);
    const int dn = d + 1;

    // --- P1a: stage slab d+1 from prefetched regs into buf[cur^1];
    //          fuse smooth-L1; issue prefetch of slab d+2 ---
    if (tid < 208) {
      if ((unsigned)dn < (unsigned)DIMZ && dn < dend) {
        const float4 u = f4add(xq, yq);
        const float4 v = f4sub(xq, yq);
        us4[(cur ^ 1) * BUF + sr * XS4 + sc4] = u;
        vs4[(cur ^ 1) * BUF + sr * XS4 + sc4] = v;
        if (dn >= c0 && dn < c0 + CD && l1own) {
          const float a0 = fabsf(v.x), a1 = fabsf(v.y);
          const float a2 = fabsf(v.z), a3 = fabsf(v.w);
          l1loc += (a0 < 1.f) ? 0.5f * a0 * a0 : a0 - 0.5f;
          l1loc += (a1 < 1.f) ? 0.5f * a1 * a1 : a1 - 0.5f;
          l1loc += (a2 < 1.f) ? 0.5f * a2 * a2 : a2 - 0.5f;
          l1loc += (a3 < 1.f) ? 0.5f * a3 * a3 : a3 - 0.5f;
        }
      }
      const int d2 = d + 2;
      if (sok && (unsigned)d2 < (unsigned)DIMZ && d2 < dend) {
        const size_t g = sgoff + (size_t)d2 * PLANE;
        xq = *(const float4*)(X + g);   // in flight across W/H/ring of this iter
        yq = *(const float4*)(Y + g);
      } else {
        xq = make_float4(0.f, 0.f, 0.f, 0.f);
        yq = make_float4(0.f, 0.f, 0.f, 0.f);
      }
    }

    // --- P1b: W-pass of slab d from buf[cur] into wpf[pp]: 104 thr x 4 out ---
    if (dval && tid < 104) {
      const int wr = tid >> 2, wg = tid & 3;
      const int rb = cur * BUF + wr * XS4 + wg;
      const int o  = pp * WPB + wr * WPS + (wg << 2);
      float su[4], sv[4], suu[4], svv[4];
      float t[20];
      {  // field u
        float4 q;
        q = us4[rb    ]; t[0]=q.x;  t[1]=q.y;  t[2]=q.z;  t[3]=q.w;
        q = us4[rb + 1]; t[4]=q.x;  t[5]=q.y;  t[6]=q.z;  t[7]=q.w;
        q = us4[rb + 2]; t[8]=q.x;  t[9]=q.y;  t[10]=q.z; t[11]=q.w;
        q = us4[rb + 3]; t[12]=q.x; t[13]=q.y; t[14]=q.z; t[15]=q.w;
        q = us4[rb + 4]; t[16]=q.x; t[17]=q.y; t[18]=q.z; t[19]=q.w;
        float s = 0.f, ss = 0.f;
#pragma unroll
        for (int j = 3; j <= 13; ++j) { s += t[j]; ss = fmaf(t[j], t[j], ss); }
        su[0] = s; suu[0] = ss;
#pragma unroll
        for (int k = 1; k < 4; ++k) {
          const float nw = t[13 + k], od = t[2 + k];
          s += nw - od;
          ss = fmaf(nw, nw, fmaf(-od, od, ss));
          su[k] = s; suu[k] = ss;
        }
      }
      {  // field v
        float4 q;
        q = vs4[rb    ]; t[0]=q.x;  t[1]=q.y;  t[2]=q.z;  t[3]=q.w;
        q = vs4[rb + 1]; t[4]=q.x;  t[5]=q.y;  t[6]=q.z;  t[7]=q.w;
        q = vs4[rb + 2]; t[8]=q.x;  t[9]=q.y;  t[10]=q.z; t[11]=q.w;
        q = vs4[rb + 3]; t[12]=q.x; t[13]=q.y; t[14]=q.z; t[15]=q.w;
        q = vs4[rb + 4]; t[16]=q.x; t[17]=q.y; t[18]=q.z; t[19]=q.w;
        float s = 0.f, ss = 0.f;
#pragma unroll
        for (int j = 3; j <= 13; ++j) { s += t[j]; ss = fmaf(t[j], t[j], ss); }
        sv[0] = s; svv[0] = ss;
#pragma unroll
        for (int k = 1; k < 4; ++k) {
          const float nw = t[13 + k], od = t[2 + k];
          s += nw - od;
          ss = fmaf(nw, nw, fmaf(-od, od, ss));
          sv[k] = s; svv[k] = ss;
        }
      }
#pragma unroll
      for (int k = 0; k < 4; ++k)
        wpf[o + k] = make_float4(su[k], sv[k], suu[k], svv[k]);
    }
    __syncthreads();   // B1 (the ONLY barrier): wpf[pp] complete; buf[cur] free

    // --- P2: H-pass: 64 threads x 4 sliding outputs -> Sb[pp] ---
    if (dval && tid < 64) {
      const int g = tid >> 4, w = tid & 15;
      const int base = pp * WPB + (g << 2) * WPS + w;
      const int ob   = pp * (TS * TS);
      const float4 T0 = wpf[base];
      const float4 T1 = wpf[base + WPS];
      const float4 T2 = wpf[base + 2 * WPS];
      float4 S = f4add(f4add(T0, T1), T2);
#pragma unroll
      for (int t = 3; t <= 10; ++t) S = f4add(S, wpf[base + t * WPS]);
      Sb[ob + ((g << 2) + 0) * TS + w] = S;
      S = f4sub(f4add(S, wpf[base + 11 * WPS]), T0);
      Sb[ob + ((g << 2) + 1) * TS + w] = S;
      S = f4sub(f4add(S, wpf[base + 12 * WPS]), T1);
      Sb[ob + ((g << 2) + 2) * TS + w] = S;
      S = f4sub(f4add(S, wpf[base + 13 * WPS]), T2);
      Sb[ob + ((g << 2) + 3) * TS + w] = S;
    }

    // --- P3 (pipelined): consume Sb[pp^1] = slab d-1; ring update; SSIM ---
    float4 Sv = make_float4(0.f, 0.f, 0.f, 0.f);
    if (d > d0 && (unsigned)(d - 1) < (unsigned)DIMZ)
      Sv = Sb[(pp ^ 1) * (TS * TS) + tid];
    switch (ph) {
      RING_CASE(0) RING_CASE(1) RING_CASE(2) RING_CASE(3) RING_CASE(4)
      RING_CASE(5) RING_CASE(6) RING_CASE(7) RING_CASE(8) RING_CASE(9)
      RING_CASE(10)
    }
    ph = (ph == 10) ? 0 : ph + 1;

    // --- SSIM for output voxel dc = (d-1)-5 (u/v algebra) ---
    if (d > c0 + PAD) {
      const float mu_u = sums.x * inv, mu_v = sums.y * inv;
      const float Euu  = sums.z * inv, Evv  = sums.w * inv;
      const float P = mu_u * mu_u, Q = mu_v * mu_v;
      const float sgu = Euu - P, sgv = Evv - Q;
      const float num = (0.5f * (P - Q) + c1) * (0.5f * (sgu - sgv) + c2);
      const float den = (0.5f * (P + Q) + c1) * (0.5f * (sgu + sgv) + c2);
      const float ssim = num * __builtin_amdgcn_rcpf(den + 1e-8f);
      const float val  = 0.5f * (1.f - ssim);
      ssloc += fminf(fmaxf(val, 0.f), 1.f);
    }

    cur ^= 1;
    pp  ^= 1;
  }

  // --- block reduction -> per-block partials ---
#pragma unroll
  for (int off = 32; off > 0; off >>= 1) {
    ssloc += __shfl_down(ssloc, off, 64);
    l1loc += __shfl_down(l1loc, off, 64);
  }
  __syncthreads();                 // LDS compute use done; reuse us4 as scratch
  float* scr = (float*)us4;
  const int lane = tid & 63, wv = tid >> 6;
  if (lane == 0) {
    scr[wv * 2]     = ssloc;
    scr[wv * 2 + 1] = l1loc;
  }
  __syncthreads();
  if (tid == 0) {
    pssim[bx] = scr[0] + scr[2] + scr[4] + scr[6];
    pl1[bx]   = scr[1] + scr[3] + scr[5] + scr[7];
  }
}

// Final: reduce 1000 + 1000 partials in double, emit scalar loss.
__global__ __launch_bounds__(256) void final_reduce(const float* __restrict__ pssim,
                                                    const float* __restrict__ pl1,
                                                    float* __restrict__ out) {
  double s = 0.0, l = 0.0;
  for (int i = threadIdx.x; i < NBLK; i += 256) {
    s += (double)pssim[i];
    l += (double)pl1[i];
  }
#pragma unroll
  for (int off = 32; off > 0; off >>= 1) {
    s += __shfl_down(s, off, 64);
    l += __shfl_down(l, off, 64);
  }
  __shared__ double sm[8];
  const int lane = threadIdx.x & 63, wv = threadIdx.x >> 6;
  if (lane == 0) { sm[wv * 2] = s; sm[wv * 2 + 1] = l; }
  __syncthreads();
  if (threadIdx.x == 0) {
    const double ssm = (sm[0] + sm[2] + sm[4] + sm[6]) / (double)NTOT;
    const double l1m = (sm[1] + sm[3] + sm[5] + sm[7]) / (double)NTOT;
    out[0] = (float)(0.85 * ssm + 0.15 * l1m);
  }
}

extern "C" void kernel_launch(void* const* d_in, const int* in_sizes, int n_in,
                              void* d_out, int out_size, void* d_ws, size_t ws_size,
                              hipStream_t stream) {
  const float* X = (const float*)d_in[0];
  const float* Y = (const float*)d_in[1];
  float* out = (float*)d_out;

  float* pssim = (float*)d_ws;        // NBLK floats
  float* pl1   = pssim + NBLK;        // NBLK floats

  fused_ssim<<<NBLK, 256, 0, stream>>>(X, Y, pssim, pl1);
  final_reduce<<<1, 256, 0, stream>>>(pssim, pl1, out);
}

// Round 21
// 141.714 us; speedup vs baseline: 1.2055x; 1.0128x over previous
//
#include <hip/hip_runtime.h>

// Shape fixed by reference: (2,1,160,160,160) fp32, window 11, zero-pad box filter.
// Fields reduced via u=x+y, v=x-y: box{u, v, u^2, v^2} packed in one float4.
// v10 = v3 (best measured: 70.3us kernel / 143.4 total) + bijective XCD swizzle:
//   bx = (blockIdx.x % 8) * 125 + blockIdx.x / 8   (NBLK = 1000 = 8 x 125 exact)
//   Consecutive dispatch -> XCDs round-robin; after remap each XCD owns a
//   CONTIGUOUS 125-block tile range (~one (ch,b) sub-volume, 205KB/slab << 4MB
//   L2), so W/H-halo refetches (2.9x overfetch: FETCH 189MB vs 65.5 ideal) hit
//   the XCD-private L2 instead of HBM. Only the block-index decode changes.
// Search journal (8 measured variants, all regressed vs v3):
//   v1 H-widen +10% | v2 global-direct +45% (VGPR cliff) | v4 rotations neutral
//   v5 +40us | v6 fused tail +24us | v7 CD40 +7us | v8 1-barrier pipe +6us
// Laws: (1) never raise total b128 wave-ops/output; (2) VGPR <= 64;
// (3) CD=32 optimal; (4) conflicts 7.4e6 inherent; (5) two dispatches.
#define DIMX 160
#define DIMY 160
#define DIMZ 160
#define BC   2
#define NTOT (BC * DIMZ * DIMY * DIMX)   // 8,192,000
#define PLANE (DIMY * DIMX)
#define PAD  5
#define TS   16                  // tile size in H and W
#define HS   26                  // TS + 2*PAD rows
#define XS4  10                  // stage row stride in float4 (8 used + 2 pad)
#define BUF  (HS * XS4)          // one u/v slab buffer in float4 (260)
#define WPS  17                  // wpf row stride in float4 (breaks bank aliasing)
#define CD   32                  // D-chunk per block
#define NCH  (DIMZ / CD)         // 5
#define NTH  (DIMY / TS)         // 10
#define NTW  (DIMX / TS)         // 10
#define NBLK (NCH * BC * NTH * NTW)  // 1000 blocks
#define NXCD 8
#define CPX  (NBLK / NXCD)       // 125 blocks per XCD (exact: 1000 % 8 == 0)

static_assert(NTOT == 8192000, "size mismatch");
static_assert(NCH * CD == DIMZ, "CD must divide DIMZ");
static_assert(NBLK % NXCD == 0, "swizzle must be bijective");

__device__ __forceinline__ float4 f4add(float4 a, float4 b) {
  return make_float4(a.x + b.x, a.y + b.y, a.z + b.z, a.w + b.w);
}
__device__ __forceinline__ float4 f4sub(float4 a, float4 b) {
  return make_float4(a.x - b.x, a.y - b.y, a.z - b.z, a.w - b.w);
}

// Ring slot update with compile-time index K (keeps ring[] in VGPRs).
#define RING_CASE(K) case K: {                 \
    sums = f4add(sums, f4sub(Sv, ring[K]));    \
    ring[K] = Sv;                              \
  } break;

__global__ __launch_bounds__(256) void fused_ssim(const float* __restrict__ X,
                                                  const float* __restrict__ Y,
                                                  float* __restrict__ pssim,
                                                  float* __restrict__ pl1) {
  __shared__ float4 us4[2 * BUF];    // double-buffered staged u slabs
  __shared__ float4 vs4[2 * BUF];    // double-buffered staged v slabs
  __shared__ float4 wpf[HS * WPS];   // W-passed {su,sv,suu,svv}, stride 17
  __shared__ float4 Sb[TS * TS];     // H-passed per-voxel field vector

  const int tid = threadIdx.x;
  // XCD-aware bijective remap: each XCD gets a contiguous tile range.
  const int bx  = (blockIdx.x % NXCD) * CPX + blockIdx.x / NXCD;
  const int tw  = bx % NTW;
  const int th  = (bx / NTW) % NTH;
  const int b   = (bx / (NTW * NTH)) % BC;
  const int ch  =  bx / (NTW * NTH * BC);
  const int h0 = th * TS, w0 = tw * TS, c0 = ch * CD;
  const size_t bbase = (size_t)b * (DIMZ * PLANE);
  const int d0 = c0 - PAD, dend = c0 + CD + PAD;

  // staging decomposition: 208 threads = 26 rows x 8 float4-cols (w0-8 .. w0+23)
  const int sr  = tid >> 3, sc4 = tid & 7;
  const int sgh = h0 - PAD + sr;
  const int sgw = w0 - 8 + (sc4 << 2);
  const bool sok = (tid < 208) && ((unsigned)sgh < (unsigned)DIMY) &&
                   ((unsigned)sgw < (unsigned)DIMX);
  const bool l1own = (sr >= PAD) && (sr < PAD + TS) && (sc4 >= 2) && (sc4 < 6);
  const size_t sgoff = bbase + (size_t)sgh * DIMX + sgw;   // only used when sok

  float4 ring[11];
#pragma unroll
  for (int k = 0; k < 11; ++k) ring[k] = make_float4(0.f, 0.f, 0.f, 0.f);
  float4 sums = make_float4(0.f, 0.f, 0.f, 0.f);
  float l1loc = 0.f, ssloc = 0.f;

  const float inv = 1.0f / 1331.0f;             // 1/11^3
  const float c1  = 0.01f / (4096.f * 4096.f);  // K1 / data_range^2 (faithful to ref)
  const float c2  = 0.03f / (4096.f * 4096.f);

  // --- prologue: stage slab d0 into buf0; leave slab d0+1 in regs ---
  float4 xq = make_float4(0.f, 0.f, 0.f, 0.f), yq = xq;
  if (sok && (unsigned)d0 < (unsigned)DIMZ) {
    const size_t g = sgoff + (size_t)d0 * PLANE;
    xq = *(const float4*)(X + g);
    yq = *(const float4*)(Y + g);
  }
  if (tid < 208 && (unsigned)d0 < (unsigned)DIMZ) {
    us4[sr * XS4 + sc4] = f4add(xq, yq);
    vs4[sr * XS4 + sc4] = f4sub(xq, yq);
    // d0 = c0-PAD < c0: never an L1-owned slab
  }
  xq = make_float4(0.f, 0.f, 0.f, 0.f); yq = xq;
  if (sok && (unsigned)(d0 + 1) < (unsigned)DIMZ) {
    const size_t g = sgoff + (size_t)(d0 + 1) * PLANE;
    xq = *(const float4*)(X + g);
    yq = *(const float4*)(Y + g);
  }
  __syncthreads();

  int cur = 0;                     // W-pass reads buf[cur]; stage writes buf[cur^1]
  int ph = (d0 + 22) % 11;         // uniform ring phase

  for (int d = d0; d < dend; ++d) {
    const bool dval = (unsigned)d < (unsigned)DIMZ;
    const int dn = d + 1;

    // --- P1a: stage slab d+1 from prefetched regs into buf[cur^1];
    //          fuse smooth-L1; issue prefetch of slab d+2 ---
    if (tid < 208) {
      if ((unsigned)dn < (unsigned)DIMZ && dn < dend) {
        const float4 u = f4add(xq, yq);
        const float4 v = f4sub(xq, yq);
        us4[(cur ^ 1) * BUF + sr * XS4 + sc4] = u;
        vs4[(cur ^ 1) * BUF + sr * XS4 + sc4] = v;
        if (dn >= c0 && dn < c0 + CD && l1own) {
          const float a0 = fabsf(v.x), a1 = fabsf(v.y);
          const float a2 = fabsf(v.z), a3 = fabsf(v.w);
          l1loc += (a0 < 1.f) ? 0.5f * a0 * a0 : a0 - 0.5f;
          l1loc += (a1 < 1.f) ? 0.5f * a1 * a1 : a1 - 0.5f;
          l1loc += (a2 < 1.f) ? 0.5f * a2 * a2 : a2 - 0.5f;
          l1loc += (a3 < 1.f) ? 0.5f * a3 * a3 : a3 - 0.5f;
        }
      }
      const int d2 = d + 2;
      if (sok && (unsigned)d2 < (unsigned)DIMZ && d2 < dend) {
        const size_t g = sgoff + (size_t)d2 * PLANE;
        xq = *(const float4*)(X + g);   // in flight across W/H/ring of this iter
        yq = *(const float4*)(Y + g);
      } else {
        xq = make_float4(0.f, 0.f, 0.f, 0.f);
        yq = make_float4(0.f, 0.f, 0.f, 0.f);
      }
    }

    // --- P1b: W-pass of slab d from buf[cur]: 104 threads x 4 outputs ---
    if (dval && tid < 104) {
      const int wr = tid >> 2, wg = tid & 3;
      const int rb = cur * BUF + wr * XS4 + wg;
      const int o  = wr * WPS + (wg << 2);
      float su[4], sv[4], suu[4], svv[4];
      float t[20];
      {  // field u
        float4 q;
        q = us4[rb    ]; t[0]=q.x;  t[1]=q.y;  t[2]=q.z;  t[3]=q.w;
        q = us4[rb + 1]; t[4]=q.x;  t[5]=q.y;  t[6]=q.z;  t[7]=q.w;
        q = us4[rb + 2]; t[8]=q.x;  t[9]=q.y;  t[10]=q.z; t[11]=q.w;
        q = us4[rb + 3]; t[12]=q.x; t[13]=q.y; t[14]=q.z; t[15]=q.w;
        q = us4[rb + 4]; t[16]=q.x; t[17]=q.y; t[18]=q.z; t[19]=q.w;
        float s = 0.f, ss = 0.f;
#pragma unroll
        for (int j = 3; j <= 13; ++j) { s += t[j]; ss = fmaf(t[j], t[j], ss); }
        su[0] = s; suu[0] = ss;
#pragma unroll
        for (int k = 1; k < 4; ++k) {
          const float nw = t[13 + k], od = t[2 + k];
          s += nw - od;
          ss = fmaf(nw, nw, fmaf(-od, od, ss));
          su[k] = s; suu[k] = ss;
        }
      }
      {  // field v
        float4 q;
        q = vs4[rb    ]; t[0]=q.x;  t[1]=q.y;  t[2]=q.z;  t[3]=q.w;
        q = vs4[rb + 1]; t[4]=q.x;  t[5]=q.y;  t[6]=q.z;  t[7]=q.w;
        q = vs4[rb + 2]; t[8]=q.x;  t[9]=q.y;  t[10]=q.z; t[11]=q.w;
        q = vs4[rb + 3]; t[12]=q.x; t[13]=q.y; t[14]=q.z; t[15]=q.w;
        q = vs4[rb + 4]; t[16]=q.x; t[17]=q.y; t[18]=q.z; t[19]=q.w;
        float s = 0.f, ss = 0.f;
#pragma unroll
        for (int j = 3; j <= 13; ++j) { s += t[j]; ss = fmaf(t[j], t[j], ss); }
        sv[0] = s; svv[0] = ss;
#pragma unroll
        for (int k = 1; k < 4; ++k) {
          const float nw = t[13 + k], od = t[2 + k];
          s += nw - od;
          ss = fmaf(nw, nw, fmaf(-od, od, ss));
          sv[k] = s; svv[k] = ss;
        }
      }
#pragma unroll
      for (int k = 0; k < 4; ++k)
        wpf[o + k] = make_float4(su[k], sv[k], suu[k], svv[k]);
    }
    __syncthreads();   // B1: wpf complete

    // --- P2: H-pass: 64 threads x 4 sliding outputs ---
    if (dval && tid < 64) {
      const int g = tid >> 4, w = tid & 15;
      const int base = (g << 2) * WPS + w;
      const float4 T0 = wpf[base];
      const float4 T1 = wpf[base + WPS];
      const float4 T2 = wpf[base + 2 * WPS];
      float4 S = f4add(f4add(T0, T1), T2);
#pragma unroll
      for (int t = 3; t <= 10; ++t) S = f4add(S, wpf[base + t * WPS]);
      Sb[((g << 2) + 0) * TS + w] = S;
      S = f4sub(f4add(S, wpf[base + 11 * WPS]), T0);
      Sb[((g << 2) + 1) * TS + w] = S;
      S = f4sub(f4add(S, wpf[base + 12 * WPS]), T1);
      Sb[((g << 2) + 2) * TS + w] = S;
      S = f4sub(f4add(S, wpf[base + 13 * WPS]), T2);
      Sb[((g << 2) + 3) * TS + w] = S;
    }
    __syncthreads();   // B2: Sb complete

    // --- P3: redistribute, D-window ring update (registers, uniform switch) ---
    float4 Sv = make_float4(0.f, 0.f, 0.f, 0.f);
    if (dval) Sv = Sb[tid];
    switch (ph) {
      RING_CASE(0) RING_CASE(1) RING_CASE(2) RING_CASE(3) RING_CASE(4)
      RING_CASE(5) RING_CASE(6) RING_CASE(7) RING_CASE(8) RING_CASE(9)
      RING_CASE(10)
    }
    ph = (ph == 10) ? 0 : ph + 1;

    // --- SSIM for output voxel dc = d-5 (u/v algebra) ---
    if (d >= c0 + PAD) {
      const float mu_u = sums.x * inv, mu_v = sums.y * inv;
      const float Euu  = sums.z * inv, Evv  = sums.w * inv;
      const float P = mu_u * mu_u, Q = mu_v * mu_v;
      const float sgu = Euu - P, sgv = Evv - Q;
      const float num = (0.5f * (P - Q) + c1) * (0.5f * (sgu - sgv) + c2);
      const float den = (0.5f * (P + Q) + c1) * (0.5f * (sgu + sgv) + c2);
      const float ssim = num * __builtin_amdgcn_rcpf(den + 1e-8f);
      const float val  = 0.5f * (1.f - ssim);
      ssloc += fminf(fmaxf(val, 0.f), 1.f);
    }

    cur ^= 1;
  }

  // --- block reduction -> per-block partials ---
#pragma unroll
  for (int off = 32; off > 0; off >>= 1) {
    ssloc += __shfl_down(ssloc, off, 64);
    l1loc += __shfl_down(l1loc, off, 64);
  }
  __syncthreads();                 // LDS compute use done; reuse us4 as scratch
  float* scr = (float*)us4;
  const int lane = tid & 63, wv = tid >> 6;
  if (lane == 0) {
    scr[wv * 2]     = ssloc;
    scr[wv * 2 + 1] = l1loc;
  }
  __syncthreads();
  if (tid == 0) {
    pssim[bx] = scr[0] + scr[2] + scr[4] + scr[6];
    pl1[bx]   = scr[1] + scr[3] + scr[5] + scr[7];
  }
}

// Final: reduce 1000 + 1000 partials in double, emit scalar loss.
__global__ __launch_bounds__(256) void final_reduce(const float* __restrict__ pssim,
                                                    const float* __restrict__ pl1,
                                                    float* __restrict__ out) {
  double s = 0.0, l = 0.0;
  for (int i = threadIdx.x; i < NBLK; i += 256) {
    s += (double)pssim[i];
    l += (double)pl1[i];
  }
#pragma unroll
  for (int off = 32; off > 0; off >>= 1) {
    s += __shfl_down(s, off, 64);
    l += __shfl_down(l, off, 64);
  }
  __shared__ double sm[8];
  const int lane = threadIdx.x & 63, wv = threadIdx.x >> 6;
  if (lane == 0) { sm[wv * 2] = s; sm[wv * 2 + 1] = l; }
  __syncthreads();
  if (threadIdx.x == 0) {
    const double ssm = (sm[0] + sm[2] + sm[4] + sm[6]) / (double)NTOT;
    const double l1m = (sm[1] + sm[3] + sm[5] + sm[7]) / (double)NTOT;
    out[0] = (float)(0.85 * ssm + 0.15 * l1m);
  }
}

extern "C" void kernel_launch(void* const* d_in, const int* in_sizes, int n_in,
                              void* d_out, int out_size, void* d_ws, size_t ws_size,
                              hipStream_t stream) {
  const float* X = (const float*)d_in[0];
  const float* Y = (const float*)d_in[1];
  float* out = (float*)d_out;

  float* pssim = (float*)d_ws;        // NBLK floats
  float* pl1   = pssim + NBLK;        // NBLK floats

  fused_ssim<<<NBLK, 256, 0, stream>>>(X, Y, pssim, pl1);
  final_reduce<<<1, 256, 0, stream>>>(pssim, pl1, out);
}